// Round 5
// baseline (910.102 us; speedup 1.0000x reference)
//
#include <hip/hip_runtime.h>
#include <hip/hip_bf16.h>
#include <cstddef>
#include <cstdint>

#define T_TOK 1024
#define HDIM  2048
#define NEXP  64
#define IDIM  768
#define TOPK  8

using f32x4 = __attribute__((ext_vector_type(4))) float;
using s16x8 = __attribute__((ext_vector_type(8))) short;

// ---- workspace layout (bytes) ----
static constexpr size_t XBF_OFF = 0;                                   // bf16 X: 4 MiB
static constexpr size_t CNT_OFF = (size_t)T_TOK * HDIM * 2;            // 64 ints
static constexpr size_t OFF_OFF = CNT_OFF + 256;                       // 65 ints
static constexpr size_t QM_OFF  = CNT_OFF + 768;                       // q_gu, q_dn, nrg
static constexpr size_t RGL_OFF = CNT_OFF + 1024;                      // rowgroup list (<=512 ints)
static constexpr size_t TOK_OFF = CNT_OFF + 4096;                      // 64*1024 ints
static constexpr size_t WT_OFF  = TOK_OFF + (size_t)NEXP * T_TOK * 4;  // 64*1024 floats
static constexpr size_t HH_OFF  = WT_OFF  + (size_t)NEXP * T_TOK * 4;  // 8192*768 bf16

__device__ __forceinline__ short f2bf(float f) {
  union { __hip_bfloat16 b; short s; } u;
  u.b = __float2bfloat16(f);
  return u.s;
}

// ---------------- router (+ fused x fp32->bf16 convert) ----------------
__global__ __launch_bounds__(256) void router_kernel(
    const float* __restrict__ X, const float* __restrict__ GW,
    __hip_bfloat16* __restrict__ Xb,
    int* __restrict__ cnt, int* __restrict__ tokl, float* __restrict__ wtl) {
  __shared__ float xs[HDIM];
  __shared__ float lg[NEXP];
  const int t = blockIdx.x;
  const int tid = threadIdx.x;
  const f32x4* xr = (const f32x4*)(X + (size_t)t * HDIM);
#pragma unroll
  for (int i = 0; i < 2; ++i) {
    f32x4 v = xr[tid + i * 256];
    *(f32x4*)&xs[(tid + i * 256) * 4] = v;
  }
  __syncthreads();
  // fused convert: write bf16 row of X
  {
    union { short h[8]; int4 q; } u;
#pragma unroll
    for (int j = 0; j < 8; ++j) u.h[j] = f2bf(xs[tid * 8 + j]);
    *(int4*)((char*)Xb + ((size_t)t * HDIM + tid * 8) * 2) = u.q;
  }
  const int wid = tid >> 6, lane = tid & 63;
  for (int ee = 0; ee < 16; ++ee) {
    const int e = wid * 16 + ee;
    const float* g = GW + (size_t)e * HDIM;
    float acc = 0.f;
    for (int i = lane; i < HDIM; i += 64) acc += xs[i] * g[i];
#pragma unroll
    for (int s = 32; s; s >>= 1) acc += __shfl_xor(acc, s);
    if (lane == 0) lg[e] = acc;
  }
  __syncthreads();
  if (tid < 64) {
    const float v = lg[tid];
    float m = v;
#pragma unroll
    for (int s = 32; s; s >>= 1) m = fmaxf(m, __shfl_xor(m, s));
    const float p = expf(v - m);
    float den = p;
#pragma unroll
    for (int s = 32; s; s >>= 1) den += __shfl_xor(den, s);
    float work = p / den;
    float my_v = 0.f; int my_e = 0;
    float topsum = 0.f;
#pragma unroll
    for (int k = 0; k < TOPK; ++k) {
      float mv = work;
#pragma unroll
      for (int s = 32; s; s >>= 1) mv = fmaxf(mv, __shfl_xor(mv, s));
      unsigned long long ball = __ballot(work == mv);
      const int idx = __ffsll(ball) - 1;   // lowest index on ties (matches lax.top_k)
      topsum += mv;
      if (tid == k) { my_v = mv; my_e = idx; }
      if (tid == idx) work = -1.f;
    }
    if (tid < TOPK) {
      const float w = my_v / topsum;
      const int slot = atomicAdd(&cnt[my_e], 1);
      tokl[my_e * T_TOK + slot] = t;
      wtl[my_e * T_TOK + slot] = w;
    }
  }
}

// ---------------- prefix scan + rowgroup list ----------------
__global__ void scan_kernel(const int* __restrict__ cnt, int* __restrict__ offs,
                            int* __restrict__ rgl, int* __restrict__ qm) {
  if (threadIdx.x == 0) {
    int a = 0, nrg = 0;
    for (int e = 0; e < NEXP; ++e) {
      offs[e] = a;
      const int ne = cnt[e];
      a += ne;
      for (int t = 0; t * 128 < ne; ++t) rgl[nrg++] = (e << 3) | t;
    }
    offs[NEXP] = a;
    qm[2] = nrg;
  }
}

// ================= gate+up GEMM + SwiGLU =================
// item = (rowgroup[e,ti], nc of 24): tile 128 rows x 32 cols per matrix.
// 4 waves = 2 row-halves x 2 K-halves (1024 each). NO LDS/barriers in K-loop:
// W fp32 -> regs (coalesced 128B runs) -> bf16 -> identity-MFMA transpose ->
// B-frags; A (Xb bf16) direct b128 loads. Combine K-halves via LDS at end.
__global__ __launch_bounds__(256, 2) void gateup_kernel(
    const __hip_bfloat16* __restrict__ Xb,
    const float* __restrict__ WG, const float* __restrict__ WU,
    const int* __restrict__ cnt, const int* __restrict__ offs,
    const int* __restrict__ tokl, const float* __restrict__ wtl,
    __hip_bfloat16* __restrict__ Hh, int* __restrict__ qm,
    const int* __restrict__ rgl) {
  __shared__ f32x4 sAcc[2][16][64];   // 32 KiB, used once per item
  __shared__ int sItem;
  const int tid = threadIdx.x, lane = tid & 63, wid = tid >> 6;
  const int m = lane >> 4, c = lane & 15;
  const int wr = wid & 1, kc = wid >> 1;
  const f32x4 z4 = {0.f, 0.f, 0.f, 0.f};
  s16x8 Ilo, Ihi;                     // identity B-fragments for transpose-mfma
#pragma unroll
  for (int j = 0; j < 8; ++j) {
    Ilo[j] = (m * 8 + j == c)      ? (short)0x3F80 : (short)0;
    Ihi[j] = (m * 8 + j == c + 16) ? (short)0x3F80 : (short)0;
  }
  const int itot = qm[2] * 24;

  for (;;) {
    __syncthreads();
    if (tid == 0) sItem = atomicAdd(&qm[0], 1);
    __syncthreads();
    const int it = sItem;
    if (it >= itot) break;
    const int rg = rgl[it / 24];
    const int e = rg >> 3, ti = rg & 7, nc = it % 24;
    const int ne = cnt[e];
    const int nrows = min(128, ne - ti * 128);
    const int nb = nc * 32;
    const int cbase = offs[e];
    const int tbase = e * T_TOK + ti * 128;

    // A pointers (token-indirect, per m-fragment)
    const short* pA[4];
#pragma unroll
    for (int mf = 0; mf < 4; ++mf) {
      const int rl = wr * 64 + mf * 16 + c;
      const int tok = tokl[tbase + min(rl, nrows - 1)];
      pA[mf] = (const short*)Xb + (size_t)tok * HDIM + kc * 1024 + m * 8;
    }
    // W pointers: row-permuted so transpose output lands in B-frag order
    const int h1 = kc * 1024 + (c >> 2) * 8 + (c & 3);
    const size_t eoff = (size_t)e * HDIM * IDIM;
    const float* pG1 = WG + eoff + (size_t)h1 * IDIM + nb + m * 8;
    const float* pG2 = pG1 + (size_t)4 * IDIM;
    const float* pU1 = WU + eoff + (size_t)h1 * IDIM + nb + m * 8;
    const float* pU2 = pU1 + (size_t)4 * IDIM;

    f32x4 acc[4][4];
#pragma unroll
    for (int i = 0; i < 4; ++i)
#pragma unroll
      for (int n = 0; n < 4; ++n) acc[i][n] = z4;

    f32x4 gE[4], uE[4], gO[4], uO[4];
    s16x8 aE[4], aO[4];

    auto loadB = [&](f32x4* g, f32x4* u, bool adv) {
      g[0] = *(const f32x4*)pG1; g[1] = *(const f32x4*)(pG1 + 4);
      g[2] = *(const f32x4*)pG2; g[3] = *(const f32x4*)(pG2 + 4);
      u[0] = *(const f32x4*)pU1; u[1] = *(const f32x4*)(pU1 + 4);
      u[2] = *(const f32x4*)pU2; u[3] = *(const f32x4*)(pU2 + 4);
      if (adv) {
        pG1 += (size_t)32 * IDIM; pG2 += (size_t)32 * IDIM;
        pU1 += (size_t)32 * IDIM; pU2 += (size_t)32 * IDIM;
      }
    };
    auto loadA = [&](s16x8* a, bool adv) {
#pragma unroll
      for (int mf = 0; mf < 4; ++mf) {
        a[mf] = *(const s16x8*)pA[mf];
        if (adv) pA[mf] += 32;
      }
    };
    auto trans = [&](const f32x4* w, s16x8& b0, s16x8& b1) {
      s16x8 a1, a2;
#pragma unroll
      for (int j = 0; j < 4; ++j) {
        a1[j] = f2bf(w[0][j]); a1[j + 4] = f2bf(w[1][j]);
        a2[j] = f2bf(w[2][j]); a2[j + 4] = f2bf(w[3][j]);
      }
      f32x4 t1a = __builtin_amdgcn_mfma_f32_16x16x32_bf16(a1, Ilo, z4, 0, 0, 0);
      f32x4 t1b = __builtin_amdgcn_mfma_f32_16x16x32_bf16(a1, Ihi, z4, 0, 0, 0);
      f32x4 t2a = __builtin_amdgcn_mfma_f32_16x16x32_bf16(a2, Ilo, z4, 0, 0, 0);
      f32x4 t2b = __builtin_amdgcn_mfma_f32_16x16x32_bf16(a2, Ihi, z4, 0, 0, 0);
#pragma unroll
      for (int r = 0; r < 4; ++r) {
        b0[r] = f2bf(t1a[r]); b0[r + 4] = f2bf(t2a[r]);
        b1[r] = f2bf(t1b[r]); b1[r + 4] = f2bf(t2b[r]);
      }
    };
    auto compute = [&](const f32x4* g, const f32x4* u, const s16x8* a) {
      s16x8 bg0, bg1, bu0, bu1;
      trans(g, bg0, bg1);
      trans(u, bu0, bu1);
#pragma unroll
      for (int mf = 0; mf < 4; ++mf) {
        acc[mf][0] = __builtin_amdgcn_mfma_f32_16x16x32_bf16(a[mf], bg0, acc[mf][0], 0, 0, 0);
        acc[mf][1] = __builtin_amdgcn_mfma_f32_16x16x32_bf16(a[mf], bg1, acc[mf][1], 0, 0, 0);
        acc[mf][2] = __builtin_amdgcn_mfma_f32_16x16x32_bf16(a[mf], bu0, acc[mf][2], 0, 0, 0);
        acc[mf][3] = __builtin_amdgcn_mfma_f32_16x16x32_bf16(a[mf], bu1, acc[mf][3], 0, 0, 0);
      }
    };

    loadB(gE, uE, true); loadA(aE, true);
    for (int s = 0; s < 32; s += 2) {
      const bool advO = (s + 2 < 32);
      loadB(gO, uO, advO); loadA(aO, advO);
      compute(gE, uE, aE);
      const bool advE = (s + 3 < 32);
      loadB(gE, uE, advE); loadA(aE, advE);
      compute(gO, uO, aO);
    }

    // combine K-halves + epilogue
    if (kc == 1) {
#pragma unroll
      for (int mf = 0; mf < 4; ++mf)
#pragma unroll
        for (int nf = 0; nf < 4; ++nf) sAcc[wr][mf * 4 + nf][lane] = acc[mf][nf];
    }
    __syncthreads();
    if (kc == 0) {
#pragma unroll
      for (int mf = 0; mf < 4; ++mf) {
#pragma unroll
        for (int nf = 0; nf < 4; ++nf) acc[mf][nf] += sAcc[wr][mf * 4 + nf][lane];
        const int rb = wr * 64 + mf * 16 + m * 4;
        const f32x4 wt4 = *(const f32x4*)&wtl[tbase + rb];
#pragma unroll
        for (int ncf = 0; ncf < 2; ++ncf) {
          const int colg = nb + ncf * 16 + c;
#pragma unroll
          for (int r = 0; r < 4; ++r) {
            const int row = rb + r;
            if (row < nrows) {
              const float g = acc[mf][ncf][r], uu = acc[mf][2 + ncf][r];
              const float h = (g / (1.f + __expf(-g))) * uu * wt4[r];
              Hh[(size_t)(cbase + ti * 128 + row) * IDIM + colg] = __float2bfloat16(h);
            }
          }
        }
      }
    }
  }
}

// ================= down GEMM + scatter =================
// item = (rowgroup, hc of 32): tile 128 rows x 64 h-cols; waves 2 rows x 2 K(i)-halves.
__global__ __launch_bounds__(256, 2) void down_kernel(
    const __hip_bfloat16* __restrict__ Hh, const float* __restrict__ WD,
    const int* __restrict__ cnt, const int* __restrict__ offs,
    const int* __restrict__ tokl, float* __restrict__ Out,
    int* __restrict__ qm, const int* __restrict__ rgl) {
  __shared__ f32x4 sAcc[2][16][64];
  __shared__ int sItem;
  const int tid = threadIdx.x, lane = tid & 63, wid = tid >> 6;
  const int m = lane >> 4, c = lane & 15;
  const int wr = wid & 1, kc = wid >> 1;
  const f32x4 z4 = {0.f, 0.f, 0.f, 0.f};
  s16x8 Ilo, Ihi;
#pragma unroll
  for (int j = 0; j < 8; ++j) {
    Ilo[j] = (m * 8 + j == c)      ? (short)0x3F80 : (short)0;
    Ihi[j] = (m * 8 + j == c + 16) ? (short)0x3F80 : (short)0;
  }
  const int itot = qm[2] * 32;

  for (;;) {
    __syncthreads();
    if (tid == 0) sItem = atomicAdd(&qm[1], 1);
    __syncthreads();
    const int it = sItem;
    if (it >= itot) break;
    const int rg = rgl[it / 32];
    const int e = rg >> 3, ti = rg & 7, hc = it % 32;
    const int ne = cnt[e];
    const int nrows = min(128, ne - ti * 128);
    const int hb = hc * 64;
    const int cbase = offs[e];
    const int tbase = e * T_TOK + ti * 128;

    const short* pA[4];
#pragma unroll
    for (int mf = 0; mf < 4; ++mf) {
      const int rl = wr * 64 + mf * 16 + c;
      pA[mf] = (const short*)Hh + (size_t)(cbase + ti * 128 + min(rl, nrows - 1)) * IDIM
               + kc * 384 + m * 8;
    }
    const int i1 = kc * 384 + (c >> 2) * 8 + (c & 3);
    const float* pD1 = WD + (size_t)e * IDIM * HDIM + (size_t)i1 * HDIM + hb + m * 8;
    const float* pD2 = pD1 + (size_t)4 * HDIM;

    f32x4 acc[4][4];
#pragma unroll
    for (int i = 0; i < 4; ++i)
#pragma unroll
      for (int n = 0; n < 4; ++n) acc[i][n] = z4;

    f32x4 dE[8], dO[8];
    s16x8 aE[4], aO[4];

    auto loadB = [&](f32x4* d, bool adv) {
      d[0] = *(const f32x4*)pD1;        d[1] = *(const f32x4*)(pD1 + 4);
      d[2] = *(const f32x4*)pD2;        d[3] = *(const f32x4*)(pD2 + 4);
      d[4] = *(const f32x4*)(pD1 + 32); d[5] = *(const f32x4*)(pD1 + 36);
      d[6] = *(const f32x4*)(pD2 + 32); d[7] = *(const f32x4*)(pD2 + 36);
      if (adv) { pD1 += (size_t)32 * HDIM; pD2 += (size_t)32 * HDIM; }
    };
    auto loadA = [&](s16x8* a, bool adv) {
#pragma unroll
      for (int mf = 0; mf < 4; ++mf) {
        a[mf] = *(const s16x8*)pA[mf];
        if (adv) pA[mf] += 32;
      }
    };
    auto trans = [&](const f32x4* w, s16x8& b0, s16x8& b1) {
      s16x8 a1, a2;
#pragma unroll
      for (int j = 0; j < 4; ++j) {
        a1[j] = f2bf(w[0][j]); a1[j + 4] = f2bf(w[1][j]);
        a2[j] = f2bf(w[2][j]); a2[j + 4] = f2bf(w[3][j]);
      }
      f32x4 t1a = __builtin_amdgcn_mfma_f32_16x16x32_bf16(a1, Ilo, z4, 0, 0, 0);
      f32x4 t1b = __builtin_amdgcn_mfma_f32_16x16x32_bf16(a1, Ihi, z4, 0, 0, 0);
      f32x4 t2a = __builtin_amdgcn_mfma_f32_16x16x32_bf16(a2, Ilo, z4, 0, 0, 0);
      f32x4 t2b = __builtin_amdgcn_mfma_f32_16x16x32_bf16(a2, Ihi, z4, 0, 0, 0);
#pragma unroll
      for (int r = 0; r < 4; ++r) {
        b0[r] = f2bf(t1a[r]); b0[r + 4] = f2bf(t2a[r]);
        b1[r] = f2bf(t1b[r]); b1[r + 4] = f2bf(t2b[r]);
      }
    };
    auto compute = [&](const f32x4* d, const s16x8* a) {
      s16x8 b0, b1, b2, b3;
      trans(d, b0, b1);
      trans(d + 4, b2, b3);
#pragma unroll
      for (int mf = 0; mf < 4; ++mf) {
        acc[mf][0] = __builtin_amdgcn_mfma_f32_16x16x32_bf16(a[mf], b0, acc[mf][0], 0, 0, 0);
        acc[mf][1] = __builtin_amdgcn_mfma_f32_16x16x32_bf16(a[mf], b1, acc[mf][1], 0, 0, 0);
        acc[mf][2] = __builtin_amdgcn_mfma_f32_16x16x32_bf16(a[mf], b2, acc[mf][2], 0, 0, 0);
        acc[mf][3] = __builtin_amdgcn_mfma_f32_16x16x32_bf16(a[mf], b3, acc[mf][3], 0, 0, 0);
      }
    };

    loadB(dE, true); loadA(aE, true);
    for (int s = 0; s < 12; s += 2) {
      const bool advO = (s + 2 < 12);
      loadB(dO, advO); loadA(aO, advO);
      compute(dE, aE);
      const bool advE = (s + 3 < 12);
      loadB(dE, advE); loadA(aE, advE);
      compute(dO, aO);
    }

    if (kc == 1) {
#pragma unroll
      for (int mf = 0; mf < 4; ++mf)
#pragma unroll
        for (int nf = 0; nf < 4; ++nf) sAcc[wr][mf * 4 + nf][lane] = acc[mf][nf];
    }
    __syncthreads();
    if (kc == 0) {
#pragma unroll
      for (int mf = 0; mf < 4; ++mf) {
#pragma unroll
        for (int nf = 0; nf < 4; ++nf) acc[mf][nf] += sAcc[wr][mf * 4 + nf][lane];
        const int rb = wr * 64 + mf * 16 + m * 4;
        const int4 tk4 = *(const int4*)&tokl[tbase + rb];
        const int tks[4] = {tk4.x, tk4.y, tk4.z, tk4.w};
#pragma unroll
        for (int r = 0; r < 4; ++r) {
          const int row = rb + r;
          if (row < nrows) {
            float* op = Out + (size_t)tks[r] * HDIM + hb + c;
#pragma unroll
            for (int nf = 0; nf < 4; ++nf)
              atomicAdd(op + nf * 16, acc[mf][nf][r]);
          }
        }
      }
    }
  }
}

extern "C" void kernel_launch(void* const* d_in, const int* in_sizes, int n_in,
                              void* d_out, int out_size, void* d_ws, size_t ws_size,
                              hipStream_t stream) {
  (void)in_sizes; (void)n_in; (void)ws_size;
  const float* X  = (const float*)d_in[0];
  const float* GW = (const float*)d_in[1];
  const float* WG = (const float*)d_in[2];
  const float* WU = (const float*)d_in[3];
  const float* WD = (const float*)d_in[4];
  float* Out = (float*)d_out;
  char* ws = (char*)d_ws;

  __hip_bfloat16* Xb = (__hip_bfloat16*)(ws + XBF_OFF);
  int*   cnt  = (int*)(ws + CNT_OFF);
  int*   offs = (int*)(ws + OFF_OFF);
  int*   qm   = (int*)(ws + QM_OFF);
  int*   rgl  = (int*)(ws + RGL_OFF);
  int*   tokl = (int*)(ws + TOK_OFF);
  float* wtl  = (float*)(ws + WT_OFF);
  __hip_bfloat16* Hh = (__hip_bfloat16*)(ws + HH_OFF);

  hipMemsetAsync(ws + CNT_OFF, 0, 1024, stream);  // cnt + offs + queue counters
  hipMemsetAsync(d_out, 0, (size_t)out_size * sizeof(float), stream);

  router_kernel<<<T_TOK, 256, 0, stream>>>(X, GW, Xb, cnt, tokl, wtl);
  scan_kernel<<<1, 64, 0, stream>>>(cnt, offs, rgl, qm);
  gateup_kernel<<<512, 256, 0, stream>>>(Xb, WG, WU, cnt, offs, tokl, wtl, Hh, qm, rgl);
  down_kernel<<<512, 256, 0, stream>>>(Hh, WD, cnt, offs, tokl, Out, qm, rgl);
}

// Round 6
// 661.896 us; speedup vs baseline: 1.3750x; 1.3750x over previous
//
#include <hip/hip_runtime.h>
#include <hip/hip_bf16.h>
#include <cstddef>
#include <cstdint>

#define T_TOK 1024
#define HDIM  2048
#define NEXP  64
#define IDIM  768
#define TOPK  8

using f32x4 = __attribute__((ext_vector_type(4))) float;
using s16x8 = __attribute__((ext_vector_type(8))) short;

// ---- workspace layout (bytes) ----
static constexpr size_t XBF_OFF = 0;                                   // bf16 X: 4 MiB
static constexpr size_t CNT_OFF = (size_t)T_TOK * HDIM * 2;            // 64 ints
static constexpr size_t OFF_OFF = CNT_OFF + 256;                       // 65 ints
static constexpr size_t QM_OFF  = CNT_OFF + 768;                       // q_gu, q_dn, nrg
static constexpr size_t RGL_OFF = CNT_OFF + 1024;                      // rowgroup list
static constexpr size_t TOK_OFF = CNT_OFF + 4096;                      // 64*1024 ints
static constexpr size_t WT_OFF  = TOK_OFF + (size_t)NEXP * T_TOK * 4;  // 64*1024 floats
static constexpr size_t HH_OFF  = WT_OFF  + (size_t)NEXP * T_TOK * 4;  // 8192*768 bf16

__device__ __forceinline__ short f2bf(float f) {
  union { __hip_bfloat16 b; short s; } u;
  u.b = __float2bfloat16(f);
  return u.s;
}
__device__ __forceinline__ void gl_lds16(const void* g, void* l) {
  __builtin_amdgcn_global_load_lds(
      (const __attribute__((address_space(1))) unsigned int*)g,
      (__attribute__((address_space(3))) unsigned int*)l, 16, 0, 0);
}
__device__ __forceinline__ void gl_lds4(const void* g, void* l) {
  __builtin_amdgcn_global_load_lds(
      (const __attribute__((address_space(1))) unsigned int*)g,
      (__attribute__((address_space(3))) unsigned int*)l, 4, 0, 0);
}
__device__ __forceinline__ void barrier_raw() {
  asm volatile("" ::: "memory");
  __builtin_amdgcn_s_barrier();
  asm volatile("" ::: "memory");
}
#define WAIT_VM36()  asm volatile("s_waitcnt vmcnt(36)" ::: "memory")
#define WAIT_VM20()  asm volatile("s_waitcnt vmcnt(20)" ::: "memory")
#define WAIT_VM18()  asm volatile("s_waitcnt vmcnt(18)" ::: "memory")
#define WAIT_VM10()  asm volatile("s_waitcnt vmcnt(10)" ::: "memory")
#define WAIT_VM0()   asm volatile("s_waitcnt vmcnt(0)" ::: "memory")
#define WAIT_LGKM0() asm volatile("s_waitcnt lgkmcnt(0)" ::: "memory")

// ---------------- router (+ fused fp32->bf16 convert of X) ----------------
__global__ __launch_bounds__(256) void router_kernel(
    const float* __restrict__ X, const float* __restrict__ GW,
    __hip_bfloat16* __restrict__ Xb,
    int* __restrict__ cnt, int* __restrict__ tokl, float* __restrict__ wtl) {
  __shared__ float xs[HDIM];
  __shared__ float lg[NEXP];
  const int t = blockIdx.x;
  const int tid = threadIdx.x;
  const f32x4* xr = (const f32x4*)(X + (size_t)t * HDIM);
#pragma unroll
  for (int i = 0; i < 2; ++i) {
    f32x4 v = xr[tid + i * 256];
    *(f32x4*)&xs[(tid + i * 256) * 4] = v;
  }
  __syncthreads();
  {
    union { short h[8]; int4 q; } u;
#pragma unroll
    for (int j = 0; j < 8; ++j) u.h[j] = f2bf(xs[tid * 8 + j]);
    *(int4*)((char*)Xb + ((size_t)t * HDIM + tid * 8) * 2) = u.q;
  }
  const int wid = tid >> 6, lane = tid & 63;
  for (int ee = 0; ee < 16; ++ee) {
    const int e = wid * 16 + ee;
    const float* g = GW + (size_t)e * HDIM;
    float acc = 0.f;
    for (int i = lane; i < HDIM; i += 64) acc += xs[i] * g[i];
#pragma unroll
    for (int s = 32; s; s >>= 1) acc += __shfl_xor(acc, s);
    if (lane == 0) lg[e] = acc;
  }
  __syncthreads();
  if (tid < 64) {
    const float v = lg[tid];
    float m = v;
#pragma unroll
    for (int s = 32; s; s >>= 1) m = fmaxf(m, __shfl_xor(m, s));
    const float p = expf(v - m);
    float den = p;
#pragma unroll
    for (int s = 32; s; s >>= 1) den += __shfl_xor(den, s);
    float work = p / den;
    float my_v = 0.f; int my_e = 0;
    float topsum = 0.f;
#pragma unroll
    for (int k = 0; k < TOPK; ++k) {
      float mv = work;
#pragma unroll
      for (int s = 32; s; s >>= 1) mv = fmaxf(mv, __shfl_xor(mv, s));
      unsigned long long ball = __ballot(work == mv);
      const int idx = __ffsll(ball) - 1;   // lowest index on ties (matches lax.top_k)
      topsum += mv;
      if (tid == k) { my_v = mv; my_e = idx; }
      if (tid == idx) work = -1.f;
    }
    if (tid < TOPK) {
      const float w = my_v / topsum;
      const int slot = atomicAdd(&cnt[my_e], 1);
      tokl[my_e * T_TOK + slot] = t;
      wtl[my_e * T_TOK + slot] = w;
    }
  }
}

// ---------------- prefix scan + rowgroup list ----------------
__global__ void scan_kernel(const int* __restrict__ cnt, int* __restrict__ offs,
                            int* __restrict__ rgl, int* __restrict__ qm) {
  if (threadIdx.x == 0) {
    int a = 0, nrg = 0;
    for (int e = 0; e < NEXP; ++e) {
      offs[e] = a;
      const int ne = cnt[e];
      a += ne;
      for (int t = 0; t * 128 < ne; ++t) rgl[nrg++] = (e << 3) | t;
    }
    offs[NEXP] = a;
    qm[2] = nrg;
  }
}

// ================= gate+up GEMM + SwiGLU =================
// item = (rowgroup, nc of 12): BM=128, BN=64 per matrix, BK=32.
// B staged via WIDTH-4 global_load_lds: 1 inst = 1 contiguous 256B row
// segment. LDS B rows at 264B stride (2-way bank). A via width-16 (L2).
// 2 buffers x 25088B, depth-2, IPW=18, double-barrier counted-vmcnt body.
#define GU_NB    64
#define GU_BUFSZ 25088
#define GU_NCI   12

__global__ __launch_bounds__(256, 3) void gateup_kernel(
    const __hip_bfloat16* __restrict__ Xb,
    const float* __restrict__ WG, const float* __restrict__ WU,
    const int* __restrict__ cnt, const int* __restrict__ offs,
    const int* __restrict__ tokl, const float* __restrict__ wtl,
    __hip_bfloat16* __restrict__ Hh, int* __restrict__ qm,
    const int* __restrict__ rgl) {
  __shared__ __align__(16) char sL[2 * GU_BUFSZ];
  __shared__ int sItem;
  const int tid = threadIdx.x, lane = tid & 63, wid = tid >> 6;
  const int m = lane >> 4, c = lane & 15;
  const int bm = wid >> 1;              // which matrix this wave stages
  const int brow0 = (wid & 1) * 16;     // staged row base
  // A fragment byte-offsets (rows wid*32 + mi*16 + c, k-chunk m, R3 swizzle)
  int aoffs[2];
#pragma unroll
  for (int mi = 0; mi < 2; ++mi) {
    const int row = wid * 32 + mi * 16 + c;
    aoffs[mi] = row * 64 + ((m ^ (c & 3)) << 4);
  }
  const int bkbase = (m * 8) * 264 + c * 4;   // + j*264 + nf*64 + mat*8448
  const int achk = (lane & 3) ^ ((lane >> 2) & 3);
  const int itot = qm[2] * GU_NCI;

  for (;;) {
    __syncthreads();
    if (tid == 0) sItem = atomicAdd(&qm[0], 1);
    __syncthreads();
    const int it = sItem;
    if (it >= itot) break;
    const int rg = rgl[it / GU_NCI];
    const int e = rg >> 3, ti = rg & 7, nc = it % GU_NCI;
    const int ne = cnt[e];
    const int nrows = min(128, ne - ti * 128);
    const int nb = nc * 64;
    const int cbase = offs[e] + ti * 128;
    const int tbase = e * T_TOK + ti * 128;

    // A per-lane source pointers (2 insts of 16 rows each)
    const int r0 = wid * 32 + (lane >> 2);
    const __hip_bfloat16* pa0 = Xb + (size_t)tokl[tbase + min(r0, nrows - 1)] * HDIM + achk * 8;
    const __hip_bfloat16* pa1 = Xb + (size_t)tokl[tbase + min(r0 + 16, nrows - 1)] * HDIM + achk * 8;
    // B per-lane source (wave: matrix bm, rows brow0..brow0+15; 1 row/inst)
    const float* pb = (bm ? WU : WG) + (size_t)e * HDIM * IDIM
                      + (size_t)brow0 * IDIM + nb + lane;

    f32x4 acc[2][2][4];
#pragma unroll
    for (int i = 0; i < 2; ++i)
#pragma unroll
      for (int mt = 0; mt < 2; ++mt)
#pragma unroll
        for (int n = 0; n < 4; ++n)
#pragma unroll
          for (int r = 0; r < 4; ++r) acc[i][mt][n][r] = 0.f;

    auto issue = [&](int b) {
      char* bb = sL + (b & 1) * GU_BUFSZ;
      gl_lds16(pa0, bb + wid * 2048);
      gl_lds16(pa1, bb + wid * 2048 + 1024);
      pa0 += 32; pa1 += 32;
      const float* p = pb;
      char* bd = bb + 8192 + bm * 8448 + brow0 * 264;
#pragma unroll
      for (int r = 0; r < 16; ++r) {
        gl_lds4(p, bd);
        p += IDIM; bd += 264;
      }
      pb += (size_t)32 * IDIM;
    };

    issue(0); issue(1);
    for (int t = 0; t < GU_NB; ++t) {
      if (t < GU_NB - 1) { WAIT_VM18(); } else { WAIT_VM0(); }
      barrier_raw();
      const char* bb = sL + (t & 1) * GU_BUFSZ;
      s16x8 af[2];
      af[0] = *(const s16x8*)(bb + aoffs[0]);
      af[1] = *(const s16x8*)(bb + aoffs[1]);
      s16x8 bf[2][4];
#pragma unroll
      for (int mt = 0; mt < 2; ++mt)
#pragma unroll
        for (int nf = 0; nf < 4; ++nf) {
          const char* base = bb + 8192 + mt * 8448 + bkbase + nf * 64;
          union { short h[8]; s16x8 v; } u;
#pragma unroll
          for (int j = 0; j < 8; ++j)
            u.h[j] = f2bf(*(const float*)(base + j * 264));
          bf[mt][nf] = u.v;
        }
      WAIT_LGKM0();
      barrier_raw();
      if (t + 2 < GU_NB) issue(t + 2);
#pragma unroll
      for (int mi = 0; mi < 2; ++mi)
#pragma unroll
        for (int mt = 0; mt < 2; ++mt)
#pragma unroll
          for (int nf = 0; nf < 4; ++nf)
            acc[mi][mt][nf] = __builtin_amdgcn_mfma_f32_16x16x32_bf16(
                af[mi], bf[mt][nf], acc[mi][mt][nf], 0, 0, 0);
    }

    // epilogue: h = silu(g) * u * wt -> bf16 Hh (compact rows)
#pragma unroll
    for (int mi = 0; mi < 2; ++mi) {
      const int rb = wid * 32 + mi * 16 + m * 4;
      const f32x4 wt4 = *(const f32x4*)&wtl[tbase + rb];
#pragma unroll
      for (int nf = 0; nf < 4; ++nf) {
        const int colg = nb + nf * 16 + c;
#pragma unroll
        for (int r = 0; r < 4; ++r) {
          const int row = rb + r;
          if (row < nrows) {
            const float g = acc[mi][0][nf][r], uu = acc[mi][1][nf][r];
            const float h = (g / (1.f + __expf(-g))) * uu * wt4[r];
            Hh[(size_t)(cbase + row) * IDIM + colg] = __float2bfloat16(h);
          }
        }
      }
    }
  }
}

// ================= down GEMM + scatter =================
// item = (rowgroup, hc of 32): BM=128, BN=64, BK=32. Width-4 B staging,
// 3 buffers x 16640B, depth-3, IPW=10.
#define DN_NB    24
#define DN_BUFSZ 16640
#define DN_NCI   32

__global__ __launch_bounds__(256, 3) void down_kernel(
    const __hip_bfloat16* __restrict__ Hh, const float* __restrict__ WD,
    const int* __restrict__ cnt, const int* __restrict__ offs,
    const int* __restrict__ tokl, float* __restrict__ Out,
    int* __restrict__ qm, const int* __restrict__ rgl) {
  __shared__ __align__(16) char sL[3 * DN_BUFSZ];
  __shared__ int sItem;
  const int tid = threadIdx.x, lane = tid & 63, wid = tid >> 6;
  const int m = lane >> 4, c = lane & 15;
  int aoffs[2];
#pragma unroll
  for (int mi = 0; mi < 2; ++mi) {
    const int row = wid * 32 + mi * 16 + c;
    aoffs[mi] = row * 64 + ((m ^ (c & 3)) << 4);
  }
  const int bkbase = (m * 8) * 264 + c * 4;
  const int achk = (lane & 3) ^ ((lane >> 2) & 3);
  const int itot = qm[2] * DN_NCI;

  for (;;) {
    __syncthreads();
    if (tid == 0) sItem = atomicAdd(&qm[1], 1);
    __syncthreads();
    const int it = sItem;
    if (it >= itot) break;
    const int rg = rgl[it / DN_NCI];
    const int e = rg >> 3, ti = rg & 7, hc = it % DN_NCI;
    const int ne = cnt[e];
    const int nrows = min(128, ne - ti * 128);
    const int hb = hc * 64;
    const int cbase = offs[e] + ti * 128;
    const int tbase = e * T_TOK + ti * 128;

    const int r0 = wid * 32 + (lane >> 2);
    const __hip_bfloat16* pa0 = Hh + (size_t)(cbase + min(r0, nrows - 1)) * IDIM + achk * 8;
    const __hip_bfloat16* pa1 = Hh + (size_t)(cbase + min(r0 + 16, nrows - 1)) * IDIM + achk * 8;
    const float* pb = WD + (size_t)e * IDIM * HDIM + (size_t)(wid * 8) * HDIM + hb + lane;

    f32x4 acc[2][4];
#pragma unroll
    for (int i = 0; i < 2; ++i)
#pragma unroll
      for (int n = 0; n < 4; ++n)
#pragma unroll
        for (int r = 0; r < 4; ++r) acc[i][n][r] = 0.f;

    int ibuf = 0;
    auto issue = [&]() {
      char* bb = sL + ibuf * DN_BUFSZ;
      ibuf = (ibuf == 2) ? 0 : ibuf + 1;
      gl_lds16(pa0, bb + wid * 2048);
      gl_lds16(pa1, bb + wid * 2048 + 1024);
      pa0 += 32; pa1 += 32;
      const float* p = pb;
      char* bd = bb + 8192 + (wid * 8) * 264;
#pragma unroll
      for (int r = 0; r < 8; ++r) {
        gl_lds4(p, bd);
        p += HDIM; bd += 264;
      }
      pb += (size_t)32 * HDIM;
    };

    issue(); issue(); issue();
    int cbuf = 0;
    for (int t = 0; t < DN_NB; ++t) {
      if (t < DN_NB - 2) { WAIT_VM20(); }
      else if (t == DN_NB - 2) { WAIT_VM10(); }
      else { WAIT_VM0(); }
      barrier_raw();
      const char* bb = sL + cbuf * DN_BUFSZ;
      cbuf = (cbuf == 2) ? 0 : cbuf + 1;
      s16x8 af[2];
      af[0] = *(const s16x8*)(bb + aoffs[0]);
      af[1] = *(const s16x8*)(bb + aoffs[1]);
      s16x8 bf[4];
#pragma unroll
      for (int nf = 0; nf < 4; ++nf) {
        const char* base = bb + 8192 + bkbase + nf * 64;
        union { short h[8]; s16x8 v; } u;
#pragma unroll
        for (int j = 0; j < 8; ++j)
          u.h[j] = f2bf(*(const float*)(base + j * 264));
        bf[nf] = u.v;
      }
      WAIT_LGKM0();
      barrier_raw();
      if (t + 3 < DN_NB) issue();
#pragma unroll
      for (int mi = 0; mi < 2; ++mi)
#pragma unroll
        for (int nf = 0; nf < 4; ++nf)
          acc[mi][nf] = __builtin_amdgcn_mfma_f32_16x16x32_bf16(
              af[mi], bf[nf], acc[mi][nf], 0, 0, 0);
    }

    // epilogue: fp32 atomic scatter into Out
#pragma unroll
    for (int mi = 0; mi < 2; ++mi) {
      const int rb = wid * 32 + mi * 16 + m * 4;
      const int4 tk4 = *(const int4*)&tokl[tbase + rb];
      const int tks[4] = {tk4.x, tk4.y, tk4.z, tk4.w};
#pragma unroll
      for (int r = 0; r < 4; ++r) {
        const int row = rb + r;
        if (row < nrows) {
          float* op = Out + (size_t)tks[r] * HDIM + hb + c;
#pragma unroll
          for (int nf = 0; nf < 4; ++nf)
            atomicAdd(op + nf * 16, acc[mi][nf][r]);
        }
      }
    }
  }
}

extern "C" void kernel_launch(void* const* d_in, const int* in_sizes, int n_in,
                              void* d_out, int out_size, void* d_ws, size_t ws_size,
                              hipStream_t stream) {
  (void)in_sizes; (void)n_in; (void)ws_size;
  const float* X  = (const float*)d_in[0];
  const float* GW = (const float*)d_in[1];
  const float* WG = (const float*)d_in[2];
  const float* WU = (const float*)d_in[3];
  const float* WD = (const float*)d_in[4];
  float* Out = (float*)d_out;
  char* ws = (char*)d_ws;

  __hip_bfloat16* Xb = (__hip_bfloat16*)(ws + XBF_OFF);
  int*   cnt  = (int*)(ws + CNT_OFF);
  int*   offs = (int*)(ws + OFF_OFF);
  int*   qm   = (int*)(ws + QM_OFF);
  int*   rgl  = (int*)(ws + RGL_OFF);
  int*   tokl = (int*)(ws + TOK_OFF);
  float* wtl  = (float*)(ws + WT_OFF);
  __hip_bfloat16* Hh = (__hip_bfloat16*)(ws + HH_OFF);

  hipMemsetAsync(ws + CNT_OFF, 0, 1024, stream);  // cnt + offs + queues
  hipMemsetAsync(d_out, 0, (size_t)out_size * sizeof(float), stream);

  router_kernel<<<T_TOK, 256, 0, stream>>>(X, GW, Xb, cnt, tokl, wtl);
  scan_kernel<<<1, 64, 0, stream>>>(cnt, offs, rgl, qm);
  gateup_kernel<<<416, 256, 0, stream>>>(Xb, WG, WU, cnt, offs, tokl, wtl, Hh, qm, rgl);
  down_kernel<<<544, 256, 0, stream>>>(Hh, WD, cnt, offs, tokl, Out, qm, rgl);
}